// Round 8
// baseline (585.391 us; speedup 1.0000x reference)
//
#include <hip/hip_runtime.h>
#include <hip/hip_bf16.h>
#include <stdint.h>

typedef unsigned short u16;
typedef short s16x8 __attribute__((ext_vector_type(8)));
typedef u16 u16x8 __attribute__((ext_vector_type(8)));
typedef u16 u16x4 __attribute__((ext_vector_type(4)));
typedef float f32x4 __attribute__((ext_vector_type(4)));

__device__ __forceinline__ u16 f2bf(float f) {
  union { float f; uint32_t u; } c; c.f = f;
  uint32_t u = c.u;
  u = u + 0x7fffu + ((u >> 16) & 1u);   // round-to-nearest-even
  return (u16)(u >> 16);
}
__device__ __forceinline__ float bf2f(u16 b) {
  union { uint32_t u; float f; } c; c.u = ((uint32_t)b) << 16;
  return c.f;
}

// async global->LDS, 16B per lane. LDS dest must be wave-uniform base + lane*16.
__device__ __forceinline__ void gld_lds16(const u16* g, u16* l) {
  __builtin_amdgcn_global_load_lds(
      (const __attribute__((address_space(1))) uint32_t*)g,
      (__attribute__((address_space(3))) uint32_t*)l,
      16, 0, 0);
}

// ---------------------------------------------------------------------------
// fp32 -> bf16 convert, 8 elems/thread
// ---------------------------------------------------------------------------
__global__ __launch_bounds__(256) void cvt_f32_to_bf16(
    const float* __restrict__ in, u16* __restrict__ out, long n8) {
  long i = (long)blockIdx.x * blockDim.x + threadIdx.x;
  if (i >= n8) return;
  const float4 a = ((const float4*)in)[i * 2];
  const float4 b = ((const float4*)in)[i * 2 + 1];
  u16x8 r;
  r[0] = f2bf(a.x); r[1] = f2bf(a.y); r[2] = f2bf(a.z); r[3] = f2bf(a.w);
  r[4] = f2bf(b.x); r[5] = f2bf(b.y); r[6] = f2bf(b.z); r[7] = f2bf(b.w);
  *(u16x8*)&out[i * 8] = r;
}

// 4 weight matrices (1024x1024 each) in one launch: blockIdx.y selects src
__global__ __launch_bounds__(256) void cvt_w4(
    const float* __restrict__ w0, const float* __restrict__ w1,
    const float* __restrict__ w2, const float* __restrict__ w3,
    u16* __restrict__ out) {
  const float* src = (blockIdx.y == 0) ? w0 : (blockIdx.y == 1) ? w1
                   : (blockIdx.y == 2) ? w2 : w3;
  const long i = (long)blockIdx.x * blockDim.x + threadIdx.x;
  const float4 a = ((const float4*)src)[i * 2];
  const float4 b = ((const float4*)src)[i * 2 + 1];
  u16x8 r;
  r[0] = f2bf(a.x); r[1] = f2bf(a.y); r[2] = f2bf(a.z); r[3] = f2bf(a.w);
  r[4] = f2bf(b.x); r[5] = f2bf(b.y); r[6] = f2bf(b.z); r[7] = f2bf(b.w);
  *(u16x8*)&out[(long)blockIdx.y * 1048576 + i * 8] = r;
}

// ---------------------------------------------------------------------------
// row softmax over 2048 cols, bf16 in/out (in place), fp32 math.
// S already has -1e30 at masked positions (mask fused into QK epilogue).
// ---------------------------------------------------------------------------
__global__ __launch_bounds__(256) void softmax_rows(u16* __restrict__ S) {
  const long base = (long)blockIdx.x * 2048;
  const int tid = threadIdx.x;
  const int lane = tid & 63, wave = tid >> 6;
  u16x8 raw = *(const u16x8*)&S[base + tid * 8];
  float v[8];
#pragma unroll
  for (int j = 0; j < 8; ++j) v[j] = bf2f(raw[j]);
  float m = v[0];
#pragma unroll
  for (int j = 1; j < 8; ++j) m = fmaxf(m, v[j]);
#pragma unroll
  for (int off = 32; off >= 1; off >>= 1) m = fmaxf(m, __shfl_xor(m, off));
  __shared__ float red[8];
  if (lane == 0) red[wave] = m;
  __syncthreads();
  m = fmaxf(fmaxf(red[0], red[1]), fmaxf(red[2], red[3]));
  float s = 0.f;
#pragma unroll
  for (int j = 0; j < 8; ++j) { v[j] = __expf(v[j] - m); s += v[j]; }
#pragma unroll
  for (int off = 32; off >= 1; off >>= 1) s += __shfl_xor(s, off);
  if (lane == 0) red[4 + wave] = s;
  __syncthreads();
  s = (red[4] + red[5]) + (red[6] + red[7]);
  const float inv = 1.f / s;
#pragma unroll
  for (int j = 0; j < 8; ++j) raw[j] = f2bf(v[j] * inv);
  *(u16x8*)&S[base + tid * 8] = raw;
}

// ---------------------------------------------------------------------------
// 128x128x64 GEMM (bt), m97/m103 TLP structure (round-7 verified 886 TF):
// 256 thr = 4 waves (2x2), per-wave 64x64 out, single-buffered LDS,
// 2 barriers per K-tile; overlap via 5 blocks/CU co-residency.
// LDS = exactly 32 KiB (stage 2x16KiB; epilogue quarter-tile [32][132] f32
// union'd) -> 5 blocks/CU. T2 chunk-XOR swizzle (0 conflicts), T1
// XCD-bijective remap. Epilogue: LDS-staged coalesced stores; optional
// fused mask (int4 coalesced loads, 0 -> -1e30) for the QK->S GEMM.
// MODE: 0 bf16; 1 f32; 2 split KV (bn<1024 -> Kb ldC=1024; bn>=1024 -> Vt
// transposed [b][col][2048] u16x4 direct).
// ---------------------------------------------------------------------------
union __align__(16) SmemT {
  u16 stage[2][128 * 64];        // 32 KiB: A-tile, B-tile
  float epi[32 * 132];           // 16.9 KiB epilogue C-staging (quarter-tile)
};

__device__ __forceinline__ s16x8 ldsfrag(const u16* p, int r, int c8) {
  return *(const s16x8*)&p[r * 64 + ((c8 ^ (r & 7)) << 3)];
}

__device__ __forceinline__ void stage128(const u16* __restrict__ gb, int row0,
                                         int K, int k0, u16* lbuf, int tid) {
#pragma unroll
  for (int i = 0; i < 4; ++i) {
    const int f = i * 256 + tid;
    const int rl = f >> 3, s = f & 7;
    const int gc = (s ^ (rl & 7)) << 3;     // pre-swizzled global col chunk
    gld_lds16(gb + (long)(row0 + rl) * K + k0 + gc, lbuf + f * 8);
  }
}

template<bool HAS_BIAS, int MODE, bool HAS_MASK>
__global__ __launch_bounds__(256, 5) void gemm128(
    const u16* __restrict__ A, const u16* __restrict__ B,
    const float* __restrict__ bias, const float* __restrict__ bias2,
    const int* __restrict__ mask, void* __restrict__ Cv,
    void* __restrict__ Cv2,
    int M, int N, int K, long sA, long sB, long sC, long sMask, float scale) {
  __shared__ SmemT sm;
  // T1 swizzle: dispatch id -> XCD-contiguous chunk (z-major, then m, then n)
  const int nx = gridDim.x, ny = gridDim.y;
  const int did = blockIdx.x + nx * (blockIdx.y + ny * blockIdx.z);
  const int cpx = (nx * ny * gridDim.z) >> 3;       // all grids %8 == 0
  const int nf = (did & 7) * cpx + (did >> 3);
  const int b = nf / (nx * ny);
  const int rr = nf % (nx * ny);
  const int bm = (rr / ny) * 128;
  const int bn = (rr % ny) * 128;

  const u16* Ab = A + (long)b * sA;
  const u16* Bb = B + (long)b * sB;
  const int tid = threadIdx.x;
  const int lane = tid & 63, wave = tid >> 6;
  const int wm = wave >> 1, wn = wave & 1;          // 2x2 waves, 64x64 each
  const int lr = lane & 15, lk = lane >> 4;
  const int NT = K >> 6;

  f32x4 acc[4][4] = {};

  for (int t = 0; t < NT; ++t) {
    stage128(Ab, bm, K, t << 6, sm.stage[0], tid);
    stage128(Bb, bn, K, t << 6, sm.stage[1], tid);
    asm volatile("s_waitcnt vmcnt(0)" ::: "memory");
    __syncthreads();
#pragma unroll
    for (int ks = 0; ks < 2; ++ks) {
      s16x8 af[4], bg[4];
#pragma unroll
      for (int mi = 0; mi < 4; ++mi)
        af[mi] = ldsfrag(sm.stage[0], wm * 64 + mi * 16 + lr, ks * 4 + lk);
#pragma unroll
      for (int ni = 0; ni < 4; ++ni)
        bg[ni] = ldsfrag(sm.stage[1], wn * 64 + ni * 16 + lr, ks * 4 + lk);
#pragma unroll
      for (int mi = 0; mi < 4; ++mi)
#pragma unroll
        for (int ni = 0; ni < 4; ++ni)
          acc[mi][ni] = __builtin_amdgcn_mfma_f32_16x16x32_bf16(
              af[mi], bg[ni], acc[mi][ni], 0, 0, 0);
    }
    __syncthreads();
  }

  // ---------------- epilogue ----------------
  const long cb = (long)b * sC;
  if (MODE == 2 && bn >= 1024) {
    // transposed V store: Cv2[batch][col][row], 2048 rows/batch
#pragma unroll
    for (int mi = 0; mi < 4; ++mi) {
#pragma unroll
      for (int ni = 0; ni < 4; ++ni) {
        const int row0 = bm + wm * 64 + mi * 16 + (lk << 2);
        const int col2 = (bn - 1024) + wn * 64 + ni * 16 + lr;
        const float bvx = HAS_BIAS ? bias2[col2] : 0.f;
        u16x4 pk;
#pragma unroll
        for (int j = 0; j < 4; ++j) pk[j] = f2bf(acc[mi][ni][j] * scale + bvx);
        const long ad = (long)(row0 >> 11) * (2048L * 1024) +
                        (long)col2 * 2048 + (row0 & 2047);
        *(u16x4*)&((u16*)Cv2)[ad] = pk;
      }
    }
  } else {
    // quarter-tile (32 rows) LDS-staged epilogue, 4 passes
    const int ldC = (MODE == 2) ? 1024 : N;
    const int q = tid & 7, r = tid >> 3;            // q:0..7, r:0..31
#pragma unroll
    for (int h = 0; h < 4; ++h) {
      __syncthreads();                              // prior LDS use complete
      if (wm == (h >> 1)) {
        const int mi0 = (h & 1) * 2;
#pragma unroll
        for (int mm = 0; mm < 2; ++mm) {
          const int mi = mi0 + mm;
#pragma unroll
          for (int ni = 0; ni < 4; ++ni) {
            const int c = wn * 64 + ni * 16 + lr;
            const float bvx = HAS_BIAS ? bias[bn + c] : 0.f;
#pragma unroll
            for (int j = 0; j < 4; ++j)
              sm.epi[(mm * 16 + (lk << 2) + j) * 132 + c] =
                  acc[mi][ni][j] * scale + bvx;
          }
        }
      }
      __syncthreads();
      const int growi = bm + h * 32 + r;
      const long grow = cb + (long)growi * ldC + bn;
      const long mrow = HAS_MASK
          ? ((long)b * sMask + (long)growi * (long)N + bn) : 0;
#pragma unroll
      for (int ch = 0; ch < 2; ++ch) {
        const int c0 = ch * 64 + q * 8;
        const float4 x = *(const float4*)&sm.epi[r * 132 + c0];
        const float4 y = *(const float4*)&sm.epi[r * 132 + c0 + 4];
        if (MODE == 1) {
          *(float4*)&((float*)Cv)[grow + c0] = x;
          *(float4*)&((float*)Cv)[grow + c0 + 4] = y;
        } else {
          u16x8 pk;
          if (HAS_MASK) {
            const int4 ma = *(const int4*)&mask[mrow + c0];
            const int4 mb = *(const int4*)&mask[mrow + c0 + 4];
            pk[0] = f2bf(ma.x ? x.x : -1e30f);
            pk[1] = f2bf(ma.y ? x.y : -1e30f);
            pk[2] = f2bf(ma.z ? x.z : -1e30f);
            pk[3] = f2bf(ma.w ? x.w : -1e30f);
            pk[4] = f2bf(mb.x ? y.x : -1e30f);
            pk[5] = f2bf(mb.y ? y.y : -1e30f);
            pk[6] = f2bf(mb.z ? y.z : -1e30f);
            pk[7] = f2bf(mb.w ? y.w : -1e30f);
          } else {
            pk[0] = f2bf(x.x); pk[1] = f2bf(x.y);
            pk[2] = f2bf(x.z); pk[3] = f2bf(x.w);
            pk[4] = f2bf(y.x); pk[5] = f2bf(y.y);
            pk[6] = f2bf(y.z); pk[7] = f2bf(y.w);
          }
          *(u16x8*)&((u16*)Cv)[grow + c0] = pk;
        }
      }
    }
  }
}

// ---------------------------------------------------------------------------
extern "C" void kernel_launch(void* const* d_in, const int* in_sizes, int n_in,
                              void* d_out, int out_size, void* d_ws, size_t ws_size,
                              hipStream_t stream) {
  const float* query = (const float*)d_in[0];   // [8,2048,1024]
  const float* kv    = (const float*)d_in[1];   // [8,2048,1024]
  const int*   mask  = (const int*)d_in[2];     // [8,2048,2048]
  const float* Wq = (const float*)d_in[3];
  const float* bq = (const float*)d_in[4];
  const float* Wk = (const float*)d_in[5];
  const float* bk = (const float*)d_in[6];
  const float* Wv = (const float*)d_in[7];
  const float* bv = (const float*)d_in[8];
  const float* Wo = (const float*)d_in[9];
  const float* bo = (const float*)d_in[10];
  float* out = (float*)d_out;

  char* ws = (char*)d_ws;
  const size_t MB = (size_t)1 << 20;
  u16* qbf  = (u16*)(ws + 0);          // 32MB query bf16; later reused as O
  u16* kvbf = (u16*)(ws + 32 * MB);    // 32MB kv bf16
  u16* wq   = (u16*)(ws + 64 * MB);    // 2MB  (wq,wk,wv,wo contiguous)
  u16* wk   = (u16*)(ws + 66 * MB);
  u16* wo   = (u16*)(ws + 70 * MB);
  u16* Q    = (u16*)(ws + 72 * MB);    // 32MB
  u16* Kb   = (u16*)(ws + 104 * MB);   // 32MB
  u16* Vt   = (u16*)(ws + 136 * MB);   // 32MB  [8][1024][2048] bf16
  u16* S    = (u16*)(ws + 168 * MB);   // 64MB  [8][2048][2048] bf16
  u16* O    = qbf;                     // [8][2048][1024] bf16 (qbf dead by then)

  const long sQK = (long)2048 * 1024;
  const long sS  = (long)2048 * 2048;

  // 1) converts
  cvt_f32_to_bf16<<<8192, 256, 0, stream>>>(query, qbf, 2097152);
  cvt_f32_to_bf16<<<8192, 256, 0, stream>>>(kv, kvbf, 2097152);
  cvt_w4<<<dim3(512, 4, 1), 256, 0, stream>>>(Wq, Wk, Wv, Wo, wq);

  // 2) Q projection: M=16384, N=1024, K=1024
  gemm128<true, 0, false><<<dim3(128, 8, 1), 256, 0, stream>>>(
      qbf, wq, bq, nullptr, nullptr, Q, nullptr,
      16384, 1024, 1024, 0, 0, 0, 0, 1.f);

  // 3) merged K+V projection: N=2048 (B = wk||wv contiguous).
  gemm128<true, 2, false><<<dim3(128, 16, 1), 256, 0, stream>>>(
      kvbf, wk, bk, bv, nullptr, Kb, Vt,
      16384, 2048, 1024, 0, 0, 0, 0, 1.f);

  // 4) S = masked((Q K^T) * 1/32)  (mask fused: 0 -> -1e30)
  gemm128<false, 0, true><<<dim3(16, 16, 8), 256, 0, stream>>>(
      Q, Kb, nullptr, nullptr, mask, S, nullptr,
      2048, 2048, 1024, sQK, sQK, sS, sS, 0.03125f);

  // 5) row softmax (in place on S, mask already applied)
  softmax_rows<<<16384, 256, 0, stream>>>(S);

  // 6) O = P @ V   (B = Vt [1024 n-rows][2048 k], batch stride sQK)
  gemm128<false, 0, false><<<dim3(16, 8, 8), 256, 0, stream>>>(
      S, Vt, nullptr, nullptr, nullptr, O, nullptr,
      2048, 1024, 2048, sS, sQK, sQK, 0, 1.f);

  // 7) out = O @ Wo^T + bo   (fp32 output)
  gemm128<true, 1, false><<<dim3(128, 8, 1), 256, 0, stream>>>(
      O, wo, bo, nullptr, nullptr, out, nullptr,
      16384, 1024, 1024, 0, 0, 0, 0, 1.f);
}

// Round 9
// 381.178 us; speedup vs baseline: 1.5357x; 1.5357x over previous
//
#include <hip/hip_runtime.h>
#include <hip/hip_bf16.h>
#include <stdint.h>

typedef unsigned short u16;
typedef short s16x8 __attribute__((ext_vector_type(8)));
typedef u16 u16x8 __attribute__((ext_vector_type(8)));
typedef u16 u16x4 __attribute__((ext_vector_type(4)));
typedef float f32x4 __attribute__((ext_vector_type(4)));

__device__ __forceinline__ u16 f2bf(float f) {
  union { float f; uint32_t u; } c; c.f = f;
  uint32_t u = c.u;
  u = u + 0x7fffu + ((u >> 16) & 1u);   // round-to-nearest-even
  return (u16)(u >> 16);
}
__device__ __forceinline__ float bf2f(u16 b) {
  union { uint32_t u; float f; } c; c.u = ((uint32_t)b) << 16;
  return c.f;
}

// async global->LDS, 16B per lane. LDS dest must be wave-uniform base + lane*16.
__device__ __forceinline__ void gld_lds16(const u16* g, u16* l) {
  __builtin_amdgcn_global_load_lds(
      (const __attribute__((address_space(1))) uint32_t*)g,
      (__attribute__((address_space(3))) uint32_t*)l,
      16, 0, 0);
}

// ---------------------------------------------------------------------------
// fp32 -> bf16 convert, 8 elems/thread
// ---------------------------------------------------------------------------
__global__ __launch_bounds__(256) void cvt_f32_to_bf16(
    const float* __restrict__ in, u16* __restrict__ out, long n8) {
  long i = (long)blockIdx.x * blockDim.x + threadIdx.x;
  if (i >= n8) return;
  const float4 a = ((const float4*)in)[i * 2];
  const float4 b = ((const float4*)in)[i * 2 + 1];
  u16x8 r;
  r[0] = f2bf(a.x); r[1] = f2bf(a.y); r[2] = f2bf(a.z); r[3] = f2bf(a.w);
  r[4] = f2bf(b.x); r[5] = f2bf(b.y); r[6] = f2bf(b.z); r[7] = f2bf(b.w);
  *(u16x8*)&out[i * 8] = r;
}

// 4 weight matrices (1024x1024 each) in one launch: blockIdx.y selects src
__global__ __launch_bounds__(256) void cvt_w4(
    const float* __restrict__ w0, const float* __restrict__ w1,
    const float* __restrict__ w2, const float* __restrict__ w3,
    u16* __restrict__ out) {
  const float* src = (blockIdx.y == 0) ? w0 : (blockIdx.y == 1) ? w1
                   : (blockIdx.y == 2) ? w2 : w3;
  const long i = (long)blockIdx.x * blockDim.x + threadIdx.x;
  const float4 a = ((const float4*)src)[i * 2];
  const float4 b = ((const float4*)src)[i * 2 + 1];
  u16x8 r;
  r[0] = f2bf(a.x); r[1] = f2bf(a.y); r[2] = f2bf(a.z); r[3] = f2bf(a.w);
  r[4] = f2bf(b.x); r[5] = f2bf(b.y); r[6] = f2bf(b.z); r[7] = f2bf(b.w);
  *(u16x8*)&out[(long)blockIdx.y * 1048576 + i * 8] = r;
}

// ---------------------------------------------------------------------------
// row softmax over 2048 cols, bf16 in/out (in place), fp32 math.
// S already has -1e30 at masked positions (mask fused into QK epilogue).
// ---------------------------------------------------------------------------
__global__ __launch_bounds__(256) void softmax_rows(u16* __restrict__ S) {
  const long base = (long)blockIdx.x * 2048;
  const int tid = threadIdx.x;
  const int lane = tid & 63, wave = tid >> 6;
  u16x8 raw = *(const u16x8*)&S[base + tid * 8];
  float v[8];
#pragma unroll
  for (int j = 0; j < 8; ++j) v[j] = bf2f(raw[j]);
  float m = v[0];
#pragma unroll
  for (int j = 1; j < 8; ++j) m = fmaxf(m, v[j]);
#pragma unroll
  for (int off = 32; off >= 1; off >>= 1) m = fmaxf(m, __shfl_xor(m, off));
  __shared__ float red[8];
  if (lane == 0) red[wave] = m;
  __syncthreads();
  m = fmaxf(fmaxf(red[0], red[1]), fmaxf(red[2], red[3]));
  float s = 0.f;
#pragma unroll
  for (int j = 0; j < 8; ++j) { v[j] = __expf(v[j] - m); s += v[j]; }
#pragma unroll
  for (int off = 32; off >= 1; off >>= 1) s += __shfl_xor(s, off);
  if (lane == 0) red[4 + wave] = s;
  __syncthreads();
  s = (red[4] + red[5]) + (red[6] + red[7]);
  const float inv = 1.f / s;
#pragma unroll
  for (int j = 0; j < 8; ++j) raw[j] = f2bf(v[j] * inv);
  *(u16x8*)&S[base + tid * 8] = raw;
}

// ---------------------------------------------------------------------------
// 128x128x64 GEMM (bt), m97/m103 TLP structure (round-7 verified 886 TF):
// 256 thr = 4 waves (2x2), per-wave 64x64 out, single-buffered LDS,
// 2 barriers per K-tile; overlap via blocks/CU co-residency.
// LDS = exactly 32 KiB (stage 2x16KiB; epilogue quarter-tile [32][132] f32
// union'd) -> 5 blocks/CU by LDS. __launch_bounds__(256,4): VGPR cap 128
// (compiler uses 64, NO spill — (256,5) forced 48 VGPR + acc spill = round-8
// disaster); runtime occupancy still 5 blocks/CU via LDS limit.
// T2 chunk-XOR swizzle (0 conflicts), T1 XCD-bijective remap. Epilogue:
// LDS-staged coalesced stores; optional fused mask (int4, 0 -> -1e30).
// MODE: 0 bf16; 1 f32; 2 split KV (bn<1024 -> Kb ldC=1024; bn>=1024 -> Vt
// transposed [b][col][2048] u16x4 direct).
// ---------------------------------------------------------------------------
union __align__(16) SmemT {
  u16 stage[2][128 * 64];        // 32 KiB: A-tile, B-tile
  float epi[32 * 132];           // 16.9 KiB epilogue C-staging (quarter-tile)
};

__device__ __forceinline__ s16x8 ldsfrag(const u16* p, int r, int c8) {
  return *(const s16x8*)&p[r * 64 + ((c8 ^ (r & 7)) << 3)];
}

__device__ __forceinline__ void stage128(const u16* __restrict__ gb, int row0,
                                         int K, int k0, u16* lbuf, int tid) {
#pragma unroll
  for (int i = 0; i < 4; ++i) {
    const int f = i * 256 + tid;
    const int rl = f >> 3, s = f & 7;
    const int gc = (s ^ (rl & 7)) << 3;     // pre-swizzled global col chunk
    gld_lds16(gb + (long)(row0 + rl) * K + k0 + gc, lbuf + f * 8);
  }
}

template<bool HAS_BIAS, int MODE, bool HAS_MASK>
__global__ __launch_bounds__(256, 4) void gemm128(
    const u16* __restrict__ A, const u16* __restrict__ B,
    const float* __restrict__ bias, const float* __restrict__ bias2,
    const int* __restrict__ mask, void* __restrict__ Cv,
    void* __restrict__ Cv2,
    int M, int N, int K, long sA, long sB, long sC, long sMask, float scale) {
  __shared__ SmemT sm;
  // T1 swizzle: dispatch id -> XCD-contiguous chunk (z-major, then m, then n)
  const int nx = gridDim.x, ny = gridDim.y;
  const int did = blockIdx.x + nx * (blockIdx.y + ny * blockIdx.z);
  const int cpx = (nx * ny * gridDim.z) >> 3;       // all grids %8 == 0
  const int nf = (did & 7) * cpx + (did >> 3);
  const int b = nf / (nx * ny);
  const int rr = nf % (nx * ny);
  const int bm = (rr / ny) * 128;
  const int bn = (rr % ny) * 128;

  const u16* Ab = A + (long)b * sA;
  const u16* Bb = B + (long)b * sB;
  const int tid = threadIdx.x;
  const int lane = tid & 63, wave = tid >> 6;
  const int wm = wave >> 1, wn = wave & 1;          // 2x2 waves, 64x64 each
  const int lr = lane & 15, lk = lane >> 4;
  const int NT = K >> 6;

  f32x4 acc[4][4] = {};

  for (int t = 0; t < NT; ++t) {
    stage128(Ab, bm, K, t << 6, sm.stage[0], tid);
    stage128(Bb, bn, K, t << 6, sm.stage[1], tid);
    asm volatile("s_waitcnt vmcnt(0)" ::: "memory");
    __syncthreads();
#pragma unroll
    for (int ks = 0; ks < 2; ++ks) {
      s16x8 af[4], bg[4];
#pragma unroll
      for (int mi = 0; mi < 4; ++mi)
        af[mi] = ldsfrag(sm.stage[0], wm * 64 + mi * 16 + lr, ks * 4 + lk);
#pragma unroll
      for (int ni = 0; ni < 4; ++ni)
        bg[ni] = ldsfrag(sm.stage[1], wn * 64 + ni * 16 + lr, ks * 4 + lk);
#pragma unroll
      for (int mi = 0; mi < 4; ++mi)
#pragma unroll
        for (int ni = 0; ni < 4; ++ni)
          acc[mi][ni] = __builtin_amdgcn_mfma_f32_16x16x32_bf16(
              af[mi], bg[ni], acc[mi][ni], 0, 0, 0);
    }
    __syncthreads();
  }

  // ---------------- epilogue ----------------
  const long cb = (long)b * sC;
  if (MODE == 2 && bn >= 1024) {
    // transposed V store: Cv2[batch][col][row], 2048 rows/batch
#pragma unroll
    for (int mi = 0; mi < 4; ++mi) {
#pragma unroll
      for (int ni = 0; ni < 4; ++ni) {
        const int row0 = bm + wm * 64 + mi * 16 + (lk << 2);
        const int col2 = (bn - 1024) + wn * 64 + ni * 16 + lr;
        const float bvx = HAS_BIAS ? bias2[col2] : 0.f;
        u16x4 pk;
#pragma unroll
        for (int j = 0; j < 4; ++j) pk[j] = f2bf(acc[mi][ni][j] * scale + bvx);
        const long ad = (long)(row0 >> 11) * (2048L * 1024) +
                        (long)col2 * 2048 + (row0 & 2047);
        *(u16x4*)&((u16*)Cv2)[ad] = pk;
      }
    }
  } else {
    // quarter-tile (32 rows) LDS-staged epilogue, 4 passes
    const int ldC = (MODE == 2) ? 1024 : N;
    const int q = tid & 7, r = tid >> 3;            // q:0..7, r:0..31
#pragma unroll
    for (int h = 0; h < 4; ++h) {
      __syncthreads();                              // prior LDS use complete
      if (wm == (h >> 1)) {
        const int mi0 = (h & 1) * 2;
#pragma unroll
        for (int mm = 0; mm < 2; ++mm) {
          const int mi = mi0 + mm;
#pragma unroll
          for (int ni = 0; ni < 4; ++ni) {
            const int c = wn * 64 + ni * 16 + lr;
            const float bvx = HAS_BIAS ? bias[bn + c] : 0.f;
#pragma unroll
            for (int j = 0; j < 4; ++j)
              sm.epi[(mm * 16 + (lk << 2) + j) * 132 + c] =
                  acc[mi][ni][j] * scale + bvx;
          }
        }
      }
      __syncthreads();
      const int growi = bm + h * 32 + r;
      const long grow = cb + (long)growi * ldC + bn;
      const long mrow = HAS_MASK
          ? ((long)b * sMask + (long)growi * (long)N + bn) : 0;
#pragma unroll
      for (int ch = 0; ch < 2; ++ch) {
        const int c0 = ch * 64 + q * 8;
        const float4 x = *(const float4*)&sm.epi[r * 132 + c0];
        const float4 y = *(const float4*)&sm.epi[r * 132 + c0 + 4];
        if (MODE == 1) {
          *(float4*)&((float*)Cv)[grow + c0] = x;
          *(float4*)&((float*)Cv)[grow + c0 + 4] = y;
        } else {
          u16x8 pk;
          if (HAS_MASK) {
            const int4 ma = *(const int4*)&mask[mrow + c0];
            const int4 mb = *(const int4*)&mask[mrow + c0 + 4];
            pk[0] = f2bf(ma.x ? x.x : -1e30f);
            pk[1] = f2bf(ma.y ? x.y : -1e30f);
            pk[2] = f2bf(ma.z ? x.z : -1e30f);
            pk[3] = f2bf(ma.w ? x.w : -1e30f);
            pk[4] = f2bf(mb.x ? y.x : -1e30f);
            pk[5] = f2bf(mb.y ? y.y : -1e30f);
            pk[6] = f2bf(mb.z ? y.z : -1e30f);
            pk[7] = f2bf(mb.w ? y.w : -1e30f);
          } else {
            pk[0] = f2bf(x.x); pk[1] = f2bf(x.y);
            pk[2] = f2bf(x.z); pk[3] = f2bf(x.w);
            pk[4] = f2bf(y.x); pk[5] = f2bf(y.y);
            pk[6] = f2bf(y.z); pk[7] = f2bf(y.w);
          }
          *(u16x8*)&((u16*)Cv)[grow + c0] = pk;
        }
      }
    }
  }
}

// ---------------------------------------------------------------------------
extern "C" void kernel_launch(void* const* d_in, const int* in_sizes, int n_in,
                              void* d_out, int out_size, void* d_ws, size_t ws_size,
                              hipStream_t stream) {
  const float* query = (const float*)d_in[0];   // [8,2048,1024]
  const float* kv    = (const float*)d_in[1];   // [8,2048,1024]
  const int*   mask  = (const int*)d_in[2];     // [8,2048,2048]
  const float* Wq = (const float*)d_in[3];
  const float* bq = (const float*)d_in[4];
  const float* Wk = (const float*)d_in[5];
  const float* bk = (const float*)d_in[6];
  const float* Wv = (const float*)d_in[7];
  const float* bv = (const float*)d_in[8];
  const float* Wo = (const float*)d_in[9];
  const float* bo = (const float*)d_in[10];
  float* out = (float*)d_out;

  char* ws = (char*)d_ws;
  const size_t MB = (size_t)1 << 20;
  u16* qbf  = (u16*)(ws + 0);          // 32MB query bf16; later reused as O
  u16* kvbf = (u16*)(ws + 32 * MB);    // 32MB kv bf16
  u16* wq   = (u16*)(ws + 64 * MB);    // 2MB  (wq,wk,wv,wo contiguous)
  u16* wk   = (u16*)(ws + 66 * MB);
  u16* wo   = (u16*)(ws + 70 * MB);
  u16* Q    = (u16*)(ws + 72 * MB);    // 32MB
  u16* Kb   = (u16*)(ws + 104 * MB);   // 32MB
  u16* Vt   = (u16*)(ws + 136 * MB);   // 32MB  [8][1024][2048] bf16
  u16* S    = (u16*)(ws + 168 * MB);   // 64MB  [8][2048][2048] bf16
  u16* O    = qbf;                     // [8][2048][1024] bf16 (qbf dead by then)

  const long sQK = (long)2048 * 1024;
  const long sS  = (long)2048 * 2048;

  // 1) converts
  cvt_f32_to_bf16<<<8192, 256, 0, stream>>>(query, qbf, 2097152);
  cvt_f32_to_bf16<<<8192, 256, 0, stream>>>(kv, kvbf, 2097152);
  cvt_w4<<<dim3(512, 4, 1), 256, 0, stream>>>(Wq, Wk, Wv, Wo, wq);

  // 2) Q projection: M=16384, N=1024, K=1024
  gemm128<true, 0, false><<<dim3(128, 8, 1), 256, 0, stream>>>(
      qbf, wq, bq, nullptr, nullptr, Q, nullptr,
      16384, 1024, 1024, 0, 0, 0, 0, 1.f);

  // 3) merged K+V projection: N=2048 (B = wk||wv contiguous).
  gemm128<true, 2, false><<<dim3(128, 16, 1), 256, 0, stream>>>(
      kvbf, wk, bk, bv, nullptr, Kb, Vt,
      16384, 2048, 1024, 0, 0, 0, 0, 1.f);

  // 4) S = masked((Q K^T) * 1/32)  (mask fused: 0 -> -1e30)
  gemm128<false, 0, true><<<dim3(16, 16, 8), 256, 0, stream>>>(
      Q, Kb, nullptr, nullptr, mask, S, nullptr,
      2048, 2048, 1024, sQK, sQK, sS, sS, 0.03125f);

  // 5) row softmax (in place on S, mask already applied)
  softmax_rows<<<16384, 256, 0, stream>>>(S);

  // 6) O = P @ V   (B = Vt [1024 n-rows][2048 k], batch stride sQK)
  gemm128<false, 0, false><<<dim3(16, 8, 8), 256, 0, stream>>>(
      S, Vt, nullptr, nullptr, nullptr, O, nullptr,
      2048, 1024, 2048, sS, sQK, sQK, 0, 1.f);

  // 7) out = O @ Wo^T + bo   (fp32 output)
  gemm128<true, 1, false><<<dim3(128, 8, 1), 256, 0, stream>>>(
      O, wo, bo, nullptr, nullptr, out, nullptr,
      16384, 1024, 1024, 0, 0, 0, 0, 1.f);
}